// Round 7
// baseline (118.289 us; speedup 1.0000x reference)
//
#include <hip/hip_runtime.h>
#include <hip/hip_bf16.h>
#include <cstdint>

// ---------------------------------------------------------------------------
// Fused causal self-attention block (B=2, T=2048, C=1024, H=16, Dh=64), fp32 in/out.
// cvt fp32->bf16 -> QKV GEMM (Q pre-scaled) -> V-transpose -> causal flash attn -> out GEMM.
// Workspace (48MB):
//   xb/Vt @ 0     8 MB   bf16 x [4096][1024]; REUSED after gemm1 as Vt [32][64][2048]
//   wqkvb @ 8 MB  6 MB   bf16 w_qkv [3072][1024]
//   wob   @ 14MB  2 MB   bf16 w_out [1024][1024]
//   qkvb  @ 16MB 24 MB   bf16 qkv [4096][3072] (Q|K|V; Q scaled by 0.125*log2e)
//   yb    @ 40MB  8 MB   bf16 attn out [4096][1024]
// ---------------------------------------------------------------------------

typedef __bf16 bf16x8 __attribute__((ext_vector_type(8)));
typedef __bf16 bf16x2 __attribute__((ext_vector_type(2)));
typedef float  f32x4  __attribute__((ext_vector_type(4)));

#define EMB   1024
#define HEADS 16
#define HD    64
#define TT    2048
#define NROWS 4096
#define QKVN  3072
#define SCL   0.18033688f   /* 0.125 * log2(e): folded into Q at gemm1 epilogue */
#define THR   11.0f         /* defer-max threshold, log2 units */

// ---- fused fp32 -> bf16 (8 elems / thread, 3 arrays in one launch) ----
__global__ void cvt_all(const float* __restrict__ x, const float* __restrict__ wq,
                        const float* __restrict__ wo, __bf16* __restrict__ xb,
                        __bf16* __restrict__ wqb, __bf16* __restrict__ wob) {
  const int bid = blockIdx.x;
  const float* in; __bf16* out; int i;
  if (bid < 2048)      { in = x;  out = xb;  i = bid * 256 + threadIdx.x; }
  else if (bid < 3584) { in = wq; out = wqb; i = (bid - 2048) * 256 + threadIdx.x; }
  else                 { in = wo; out = wob; i = (bid - 3584) * 256 + threadIdx.x; }
  const float4* p = (const float4*)in + (size_t)i * 2;
  float4 a = p[0], b = p[1];
  bf16x8 o;
  o[0] = (__bf16)a.x; o[1] = (__bf16)a.y; o[2] = (__bf16)a.z; o[3] = (__bf16)a.w;
  o[4] = (__bf16)b.x; o[5] = (__bf16)b.y; o[6] = (__bf16)b.z; o[7] = (__bf16)b.w;
  *((bf16x8*)out + i) = o;
}

__device__ __forceinline__ void gload_lds16(const void* g, void* l) {
  __builtin_amdgcn_global_load_lds(
      (const __attribute__((address_space(1))) void*)(uintptr_t)g,
      (__attribute__((address_space(3))) void*)(uint32_t)(uintptr_t)l,
      16, 0, 0);
}

// ---- GEMM: C[M,N] = A[M,K] * Bm[N,K]^T (m97 structure + XCD swizzle) ----
template <int OUT_BF16, int SCALE_Q>
__global__ __launch_bounds__(256, 2)
void gemm_bt(const __bf16* __restrict__ A, const __bf16* __restrict__ Bm,
             void* __restrict__ Cout, int M, int N, int K) {
  __shared__ __align__(16) __bf16 As[128 * 32];
  __shared__ __align__(16) __bf16 Bs[128 * 32];
  const int tid  = threadIdx.x;
  const int lane = tid & 63;
  const int wid  = tid >> 6;
  const int wr = wid >> 1, wc = wid & 1;
  const int nwg = gridDim.x * gridDim.y;
  int flat = blockIdx.y * gridDim.x + blockIdx.x;
  flat = (flat & 7) * (nwg >> 3) + (flat >> 3);
  const int brow = (flat / gridDim.x) * 128;
  const int bcol = (flat % gridDim.x) * 128;
  const int fr = lane & 15, g = lane >> 4;

  f32x4 acc[4][4];
#pragma unroll
  for (int m = 0; m < 4; m++)
#pragma unroll
    for (int n = 0; n < 4; n++)
#pragma unroll
      for (int r = 0; r < 4; r++) acc[m][n][r] = 0.0f;

  const int c0 = tid, c1 = tid + 256;
  for (int k0 = 0; k0 < K; k0 += 32) {
    __syncthreads();
    gload_lds16(A  + (size_t)(brow + (c0 >> 2)) * K + k0 + (c0 & 3) * 8, (char*)As + c0 * 16);
    gload_lds16(A  + (size_t)(brow + (c1 >> 2)) * K + k0 + (c1 & 3) * 8, (char*)As + c1 * 16);
    gload_lds16(Bm + (size_t)(bcol + (c0 >> 2)) * K + k0 + (c0 & 3) * 8, (char*)Bs + c0 * 16);
    gload_lds16(Bm + (size_t)(bcol + (c1 >> 2)) * K + k0 + (c1 & 3) * 8, (char*)Bs + c1 * 16);
    __syncthreads();

    bf16x8 af[4], bfr[4];
#pragma unroll
    for (int m = 0; m < 4; m++)
      af[m] = *(const bf16x8*)((const char*)As + (wr * 64 + m * 16 + fr) * 64 + g * 16);
#pragma unroll
    for (int n = 0; n < 4; n++)
      bfr[n] = *(const bf16x8*)((const char*)Bs + (wc * 64 + n * 16 + fr) * 64 + g * 16);
#pragma unroll
    for (int m = 0; m < 4; m++)
#pragma unroll
      for (int n = 0; n < 4; n++)
        acc[m][n] = __builtin_amdgcn_mfma_f32_16x16x32_bf16(af[m], bfr[n], acc[m][n], 0, 0, 0);
  }

  const float qscale = (SCALE_Q && bcol < EMB) ? SCL : 1.0f;
  const int rbase = brow + wr * 64 + g * 4;
  const int cbase = bcol + wc * 64 + fr;
#pragma unroll
  for (int m = 0; m < 4; m++)
#pragma unroll
    for (int n = 0; n < 4; n++) {
      const int col = cbase + n * 16;
#pragma unroll
      for (int r = 0; r < 4; r++) {
        const int row = rbase + m * 16 + r;
        const float v = acc[m][n][r] * qscale;
        if (OUT_BF16) ((__bf16*)Cout)[(size_t)row * N + col] = (__bf16)v;
        else          ((float*)Cout)[(size_t)row * N + col]  = v;
      }
    }
}

// ---- V transpose: qkv [4096][3072] (V cols) -> Vt [32 bh][64 d][2048 t] ----
__global__ __launch_bounds__(256)
void vtrans(const __bf16* __restrict__ qkv, __bf16* __restrict__ vt) {
  __shared__ __bf16 tile[64][66];
  const int tt = blockIdx.x;
  const int bh = blockIdx.y;
  const int b = bh >> 4, h = bh & 15;
  const int tid = threadIdx.x;
  const int tl = tid >> 2, dq = (tid & 3) * 16;
  const __bf16* src = qkv + ((size_t)(b * TT + tt * 64 + tl)) * QKVN + 2 * EMB + h * HD + dq;
  bf16x8 v0 = *(const bf16x8*)src;
  bf16x8 v1 = *(const bf16x8*)(src + 8);
#pragma unroll
  for (int u = 0; u < 4; u++) {
    *(bf16x2*)&tile[tl][dq + 2 * u]     = bf16x2{v0[2 * u], v0[2 * u + 1]};
    *(bf16x2*)&tile[tl][dq + 8 + 2 * u] = bf16x2{v1[2 * u], v1[2 * u + 1]};
  }
  __syncthreads();
  const int d = tid >> 2, tc = (tid & 3) * 16;
  bf16x8 o0, o1;
#pragma unroll
  for (int j = 0; j < 8; j++) { o0[j] = tile[tc + j][d]; o1[j] = tile[tc + 8 + j][d]; }
  __bf16* dst = vt + ((size_t)bh * HD + d) * TT + tt * 64 + tc;
  *(bf16x8*)dst = o0;
  *(bf16x8*)(dst + 8) = o1;
}

// ---------------------------------------------------------------------------
// Causal flash attention v7: 32-row waves + intra-block kv-split.
// Block = chunk of 64 q rows. Wave w: row-group rg=w&1 (rows rg*32..+31),
// kv-half hb=w>>1 (A: [t*64, t*64+32), B: [t*64+32, t*64+64)), t = 0..chunk.
// Same per-wave iteration count -> barriers align. Per 32rx32kv iter: only
// 4 kf + 4 vb + 2 pa ds_read_b128 (vs 18 per 1024 row*kv before).
// Halves merged in-block via reused LDS (canonical A+B order, deterministic).
// grid = 1024 (32 chunks x 32 bh), LPT (longest chunk first), 40KB LDS.
// ---------------------------------------------------------------------------
__global__ __launch_bounds__(256, 3)
void attn_causal7(const __bf16* __restrict__ qkv, const __bf16* __restrict__ vt,
                  __bf16* __restrict__ yb) {
  // [0,8K) KA[2][4096] | [8K,16K) VA[2][4096] | [16K,24K) KB | [24K,32K) VB
  // [32K,40K) P[4][2048].  Merge phase reuses [0, 26624).
  __shared__ __align__(16) char smem[40960];

  const int tid = threadIdx.x;
  const int lane = tid & 63, w = tid >> 6;
  const int rg = w & 1, hb = w >> 1;
  const int L = blockIdx.x;
  const int bh = L & 31;
  const int chunk = 31 - (L >> 5);               // LPT: longest first
  const int b = bh >> 4, h = bh & 15;
  const size_t rowbase = (size_t)b * TT;
  const int q0 = chunk * 64 + rg * 32;           // wave's first q row
  const int fr = lane & 15, g = lane >> 4;
  const int ntiles = chunk + 1;

  // staging bases: threads stage for their own wave's kv-half
  char* Kb = smem + (hb ? 16384 : 0);
  char* Vb = smem + (hb ? 24576 : 8192);
  char* Pw = smem + 32768 + w * 2048;
  const int lc = tid & 127;                      // lane within half-pair

  // Q fragments (pre-scaled by SCL): A-frag row = q0+m*16+fr, d = kc*32+g*8..+7
  bf16x8 qf[2][2];
#pragma unroll
  for (int m2 = 0; m2 < 2; m2++)
#pragma unroll
    for (int kc = 0; kc < 2; kc++)
      qf[m2][kc] = *(const bf16x8*)(qkv + (rowbase + q0 + m2 * 16 + fr) * QKVN + h * HD + kc * 32 + g * 8);

  bf16x8 ones;
#pragma unroll
  for (int j = 0; j < 8; j++) ones[j] = (__bf16)1.0f;

  f32x4 o[2][4];           // O[q 32][d 64] frags: [m][n]
  f32x4 lacc[2];           // row-sum per m (ones-MFMA)
  float m[2][4];           // running max per (m, r)
#pragma unroll
  for (int m2 = 0; m2 < 2; m2++) {
#pragma unroll
    for (int n = 0; n < 4; n++)
#pragma unroll
      for (int r = 0; r < 4; r++) o[m2][n][r] = 0.0f;
#pragma unroll
    for (int r = 0; r < 4; r++) { lacc[m2][r] = 0.0f; m[m2][r] = -1e30f; }
  }

  auto stageKV = [&](int t, int buf) {
    const int kvg = t * 64 + hb * 32;            // global kv base of this half
#pragma unroll
    for (int i = 0; i < 2; i++) {                // K tile [32 kv][128B]
      const int c = lc + i * 128;
      const int row = c >> 3;
      const int c16 = (c & 7) ^ (row & 7);
      gload_lds16(qkv + (rowbase + kvg + row) * QKVN + EMB + h * HD + c16 * 8,
                  Kb + buf * 4096 + c * 16);
    }
#pragma unroll
    for (int i = 0; i < 2; i++) {                // V tile [64 d][64B]
      const int c = lc + i * 128;
      const int row = c >> 2;                    // d
      const int c4 = (c & 3) ^ (row & 3);
      gload_lds16(vt + ((size_t)bh * HD + row) * TT + kvg + c4 * 8,
                  Vb + buf * 4096 + c * 16);
    }
  };

  stageKV(0, 0);
  __syncthreads();

  int cur = 0;
  for (int t = 0; t < ntiles; t++) {
    if (t + 1 < ntiles) stageKV(t + 1, cur ^ 1);

    const bool active = !((t == chunk) && hb == 1 && rg == 0);  // B-half above diag
    if (active) {
      const int kv0 = t * 64 + hb * 32;
      const char* Kc = Kb + cur * 4096;
      const char* Vc = Vb + cur * 4096;
      // K fragments: B-frag col=kv=n*16+fr, k=d
      bf16x8 kf[2][2];
#pragma unroll
      for (int n = 0; n < 2; n++)
#pragma unroll
        for (int kc = 0; kc < 2; kc++)
          kf[n][kc] = *(const bf16x8*)(Kc + (n * 16 + fr) * 128 + ((((kc << 2) | g) ^ (fr & 7)) * 16));
      // S = Q K^T : [32 q][32 kv]
      f32x4 s[2][2];
#pragma unroll
      for (int m2 = 0; m2 < 2; m2++)
#pragma unroll
        for (int n = 0; n < 2; n++) {
#pragma unroll
          for (int r = 0; r < 4; r++) s[m2][n][r] = 0.0f;
#pragma unroll
          for (int kc = 0; kc < 2; kc++)
            s[m2][n] = __builtin_amdgcn_mfma_f32_16x16x32_bf16(qf[m2][kc], kf[n][kc], s[m2][n], 0, 0, 0);
        }
      // causal mask: only when this half's window crosses the wave's diagonal
      if ((t == chunk) && (hb == rg)) {
#pragma unroll
        for (int m2 = 0; m2 < 2; m2++)
#pragma unroll
          for (int n = 0; n < 2; n++)
#pragma unroll
            for (int r = 0; r < 4; r++) {
              const int qg = q0 + m2 * 16 + g * 4 + r;
              const int kg = kv0 + n * 16 + fr;
              if (kg > qg) s[m2][n][r] = -1e30f;
            }
      }
      // defer-max vote (8 row-instances)
      float pm[2][4];
#pragma unroll
      for (int m2 = 0; m2 < 2; m2++)
#pragma unroll
        for (int r = 0; r < 4; r++)
          pm[m2][r] = fmaxf(s[m2][0][r], s[m2][1][r]);
      bool okl = true;
#pragma unroll
      for (int m2 = 0; m2 < 2; m2++)
#pragma unroll
        for (int r = 0; r < 4; r++)
          okl = okl && (pm[m2][r] <= m[m2][r] + THR);
      if (!__all(okl)) {
#pragma unroll
        for (int m2 = 0; m2 < 2; m2++)
#pragma unroll
          for (int r = 0; r < 4; r++) {
            float rm = pm[m2][r];
#pragma unroll
            for (int d = 1; d < 16; d <<= 1) rm = fmaxf(rm, __shfl_xor(rm, d, 16));
            const float nm = fmaxf(m[m2][r], rm);
            const float f = exp2f(m[m2][r] - nm);
            m[m2][r] = nm;
            lacc[m2][r] *= f;
#pragma unroll
            for (int n = 0; n < 4; n++) o[m2][n][r] *= f;
          }
      }
      // P = exp2(S - m) -> wave-private LDS [32 rows][32 kv], 64B rows, xor r<<4
#pragma unroll
      for (int m2 = 0; m2 < 2; m2++)
#pragma unroll
        for (int n = 0; n < 2; n++)
#pragma unroll
          for (int r = 0; r < 4; r++) {
            const float e = exp2f(s[m2][n][r] - m[m2][r]);
            const int row = m2 * 16 + g * 4 + r;
            *(__bf16*)(Pw + row * 64 + (((n * 16 + fr) * 2) ^ (r << 4))) = (__bf16)e;
          }
      // PV: A_P[q][kv32] x B_V[kv32][d64]  + row-sum via ones
      bf16x8 pa[2];
#pragma unroll
      for (int m2 = 0; m2 < 2; m2++)
        pa[m2] = *(const bf16x8*)(Pw + (m2 * 16 + fr) * 64 + ((g ^ (fr & 3)) << 4));
      bf16x8 vbf[4];
#pragma unroll
      for (int n = 0; n < 4; n++)
        vbf[n] = *(const bf16x8*)(Vc + (n * 16 + fr) * 64 + ((g ^ (fr & 3)) << 4));
#pragma unroll
      for (int m2 = 0; m2 < 2; m2++) {
        lacc[m2] = __builtin_amdgcn_mfma_f32_16x16x32_bf16(pa[m2], ones, lacc[m2], 0, 0, 0);
#pragma unroll
        for (int n = 0; n < 4; n++)
          o[m2][n] = __builtin_amdgcn_mfma_f32_16x16x32_bf16(pa[m2], vbf[n], o[m2][n], 0, 0, 0);
      }
    }

    __syncthreads();   // compute done on cur; next tile's DMA drained
    cur ^= 1;
  }

  // ---- in-block merge of kv-halves (rows shared by waves w and w^2) ----
  char* mb = smem + rg * 13312 + lane * 208;     // 208B stride: conflict-free b128
  if (hb == 1) {
#pragma unroll
    for (int m2 = 0; m2 < 2; m2++)
#pragma unroll
      for (int n = 0; n < 4; n++)
        *(f32x4*)(mb + (m2 * 4 + n) * 16) = o[m2][n];
    *(f32x4*)(mb + 128) = lacc[0];
    *(f32x4*)(mb + 144) = lacc[1];
    f32x4 mv0, mv1;
#pragma unroll
    for (int r = 0; r < 4; r++) { mv0[r] = m[0][r]; mv1[r] = m[1][r]; }
    *(f32x4*)(mb + 160) = mv0;
    *(f32x4*)(mb + 176) = mv1;
  }
  __syncthreads();
  if (hb == 0) {
    f32x4 oB[2][4], lB[2], mB[2];
#pragma unroll
    for (int m2 = 0; m2 < 2; m2++)
#pragma unroll
      for (int n = 0; n < 4; n++)
        oB[m2][n] = *(const f32x4*)(mb + (m2 * 4 + n) * 16);
    lB[0] = *(const f32x4*)(mb + 128);
    lB[1] = *(const f32x4*)(mb + 144);
    mB[0] = *(const f32x4*)(mb + 160);
    mB[1] = *(const f32x4*)(mb + 176);
#pragma unroll
    for (int m2 = 0; m2 < 2; m2++)
#pragma unroll
      for (int r = 0; r < 4; r++) {
        const float MM = fmaxf(m[m2][r], mB[m2][r]);
        const float fA = exp2f(m[m2][r] - MM);
        const float fB = exp2f(mB[m2][r] - MM);
        const float l  = fA * lacc[m2][r] + fB * lB[m2][r];
        const float inv = __builtin_amdgcn_rcpf(l);
        const int q = q0 + m2 * 16 + g * 4 + r;
#pragma unroll
        for (int n = 0; n < 4; n++) {
          const int d = n * 16 + fr;
          const float val = (fA * o[m2][n][r] + fB * oB[m2][n][r]) * inv;
          yb[(rowbase + q) * EMB + h * HD + d] = (__bf16)val;
        }
      }
  }
}

extern "C" void kernel_launch(void* const* d_in, const int* in_sizes, int n_in,
                              void* d_out, int out_size, void* d_ws, size_t ws_size,
                              hipStream_t stream) {
  const float* x     = (const float*)d_in[0];
  const float* w_qkv = (const float*)d_in[1];
  const float* w_out = (const float*)d_in[2];
  float* out = (float*)d_out;

  char* ws = (char*)d_ws;
  __bf16* xb    = (__bf16*)(ws);                 // reused as Vt after gemm1
  __bf16* wqkvb = (__bf16*)(ws + (8ull  << 20));
  __bf16* wob   = (__bf16*)(ws + (14ull << 20));
  __bf16* qkvb  = (__bf16*)(ws + (16ull << 20));
  __bf16* yb    = (__bf16*)(ws + (40ull << 20));
  __bf16* vtb   = xb;

  cvt_all<<<4096, 256, 0, stream>>>(x, w_qkv, w_out, xb, wqkvb, wob);
  gemm_bt<1, 1><<<dim3(QKVN / 128, NROWS / 128), 256, 0, stream>>>(xb, wqkvb, qkvb, NROWS, QKVN, EMB);
  vtrans<<<dim3(TT / 64, 32), 256, 0, stream>>>(qkvb, vtb);
  attn_causal7<<<1024, 256, 0, stream>>>(qkvb, vtb, yb);
  gemm_bt<0, 0><<<dim3(EMB / 128, NROWS / 128), 256, 0, stream>>>(yb, wob, out, NROWS, EMB, EMB);
}

// Round 8
// 115.713 us; speedup vs baseline: 1.0223x; 1.0223x over previous
//
#include <hip/hip_runtime.h>
#include <hip/hip_bf16.h>
#include <cstdint>

// ---------------------------------------------------------------------------
// Fused causal self-attention block (B=2, T=2048, C=1024, H=16, Dh=64), fp32 in/out.
// cvt fp32->bf16 -> QKV GEMM (Q pre-scaled) -> V-transpose -> causal flash attn -> out GEMM.
// Workspace (48MB):
//   xb/Vt @ 0     8 MB   bf16 x [4096][1024]; REUSED after gemm1 as Vt [32][64][2048]
//   wqkvb @ 8 MB  6 MB   bf16 w_qkv [3072][1024]
//   wob   @ 14MB  2 MB   bf16 w_out [1024][1024]
//   qkvb  @ 16MB 24 MB   bf16 qkv [4096][3072] (Q|K|V; Q scaled by 0.125*log2e)
//   yb    @ 40MB  8 MB   bf16 attn out [4096][1024]
// ---------------------------------------------------------------------------

typedef __bf16 bf16x8 __attribute__((ext_vector_type(8)));
typedef __bf16 bf16x2 __attribute__((ext_vector_type(2)));
typedef float  f32x4  __attribute__((ext_vector_type(4)));

#define EMB   1024
#define HEADS 16
#define HD    64
#define TT    2048
#define NROWS 4096
#define QKVN  3072
#define SCL   0.18033688f   /* 0.125 * log2(e): folded into Q at gemm1 epilogue */
#define THR   11.0f         /* defer-max threshold, log2 units */

// ---- fused fp32 -> bf16 (8 elems / thread, 3 arrays in one launch) ----
__global__ void cvt_all(const float* __restrict__ x, const float* __restrict__ wq,
                        const float* __restrict__ wo, __bf16* __restrict__ xb,
                        __bf16* __restrict__ wqb, __bf16* __restrict__ wob) {
  const int bid = blockIdx.x;
  const float* in; __bf16* out; int i;
  if (bid < 2048)      { in = x;  out = xb;  i = bid * 256 + threadIdx.x; }
  else if (bid < 3584) { in = wq; out = wqb; i = (bid - 2048) * 256 + threadIdx.x; }
  else                 { in = wo; out = wob; i = (bid - 3584) * 256 + threadIdx.x; }
  const float4* p = (const float4*)in + (size_t)i * 2;
  float4 a = p[0], b = p[1];
  bf16x8 o;
  o[0] = (__bf16)a.x; o[1] = (__bf16)a.y; o[2] = (__bf16)a.z; o[3] = (__bf16)a.w;
  o[4] = (__bf16)b.x; o[5] = (__bf16)b.y; o[6] = (__bf16)b.z; o[7] = (__bf16)b.w;
  *((bf16x8*)out + i) = o;
}

__device__ __forceinline__ void gload_lds16(const void* g, void* l) {
  __builtin_amdgcn_global_load_lds(
      (const __attribute__((address_space(1))) void*)(uintptr_t)g,
      (__attribute__((address_space(3))) void*)(uint32_t)(uintptr_t)l,
      16, 0, 0);
}

// ---- GEMM: C[M,N] = A[M,K] * Bm[N,K]^T (m97 structure + XCD swizzle) ----
template <int OUT_BF16, int SCALE_Q>
__global__ __launch_bounds__(256, 2)
void gemm_bt(const __bf16* __restrict__ A, const __bf16* __restrict__ Bm,
             void* __restrict__ Cout, int M, int N, int K) {
  __shared__ __align__(16) __bf16 As[128 * 32];
  __shared__ __align__(16) __bf16 Bs[128 * 32];
  const int tid  = threadIdx.x;
  const int lane = tid & 63;
  const int wid  = tid >> 6;
  const int wr = wid >> 1, wc = wid & 1;
  const int nwg = gridDim.x * gridDim.y;
  int flat = blockIdx.y * gridDim.x + blockIdx.x;
  flat = (flat & 7) * (nwg >> 3) + (flat >> 3);
  const int brow = (flat / gridDim.x) * 128;
  const int bcol = (flat % gridDim.x) * 128;
  const int fr = lane & 15, g = lane >> 4;

  f32x4 acc[4][4];
#pragma unroll
  for (int m = 0; m < 4; m++)
#pragma unroll
    for (int n = 0; n < 4; n++)
#pragma unroll
      for (int r = 0; r < 4; r++) acc[m][n][r] = 0.0f;

  const int c0 = tid, c1 = tid + 256;
  for (int k0 = 0; k0 < K; k0 += 32) {
    __syncthreads();
    gload_lds16(A  + (size_t)(brow + (c0 >> 2)) * K + k0 + (c0 & 3) * 8, (char*)As + c0 * 16);
    gload_lds16(A  + (size_t)(brow + (c1 >> 2)) * K + k0 + (c1 & 3) * 8, (char*)As + c1 * 16);
    gload_lds16(Bm + (size_t)(bcol + (c0 >> 2)) * K + k0 + (c0 & 3) * 8, (char*)Bs + c0 * 16);
    gload_lds16(Bm + (size_t)(bcol + (c1 >> 2)) * K + k0 + (c1 & 3) * 8, (char*)Bs + c1 * 16);
    __syncthreads();

    bf16x8 af[4], bfr[4];
#pragma unroll
    for (int m = 0; m < 4; m++)
      af[m] = *(const bf16x8*)((const char*)As + (wr * 64 + m * 16 + fr) * 64 + g * 16);
#pragma unroll
    for (int n = 0; n < 4; n++)
      bfr[n] = *(const bf16x8*)((const char*)Bs + (wc * 64 + n * 16 + fr) * 64 + g * 16);
#pragma unroll
    for (int m = 0; m < 4; m++)
#pragma unroll
      for (int n = 0; n < 4; n++)
        acc[m][n] = __builtin_amdgcn_mfma_f32_16x16x32_bf16(af[m], bfr[n], acc[m][n], 0, 0, 0);
  }

  const float qscale = (SCALE_Q && bcol < EMB) ? SCL : 1.0f;
  const int rbase = brow + wr * 64 + g * 4;
  const int cbase = bcol + wc * 64 + fr;
#pragma unroll
  for (int m = 0; m < 4; m++)
#pragma unroll
    for (int n = 0; n < 4; n++) {
      const int col = cbase + n * 16;
#pragma unroll
      for (int r = 0; r < 4; r++) {
        const int row = rbase + m * 16 + r;
        const float v = acc[m][n][r] * qscale;
        if (OUT_BF16) ((__bf16*)Cout)[(size_t)row * N + col] = (__bf16)v;
        else          ((float*)Cout)[(size_t)row * N + col]  = v;
      }
    }
}

// ---- V transpose: qkv [4096][3072] (V cols) -> Vt [32 bh][64 d][2048 t] ----
__global__ __launch_bounds__(256)
void vtrans(const __bf16* __restrict__ qkv, __bf16* __restrict__ vt) {
  __shared__ __bf16 tile[64][66];
  const int tt = blockIdx.x;
  const int bh = blockIdx.y;
  const int b = bh >> 4, h = bh & 15;
  const int tid = threadIdx.x;
  const int tl = tid >> 2, dq = (tid & 3) * 16;
  const __bf16* src = qkv + ((size_t)(b * TT + tt * 64 + tl)) * QKVN + 2 * EMB + h * HD + dq;
  bf16x8 v0 = *(const bf16x8*)src;
  bf16x8 v1 = *(const bf16x8*)(src + 8);
#pragma unroll
  for (int u = 0; u < 4; u++) {
    *(bf16x2*)&tile[tl][dq + 2 * u]     = bf16x2{v0[2 * u], v0[2 * u + 1]};
    *(bf16x2*)&tile[tl][dq + 8 + 2 * u] = bf16x2{v1[2 * u], v1[2 * u + 1]};
  }
  __syncthreads();
  const int d = tid >> 2, tc = (tid & 3) * 16;
  bf16x8 o0, o1;
#pragma unroll
  for (int j = 0; j < 8; j++) { o0[j] = tile[tc + j][d]; o1[j] = tile[tc + 8 + j][d]; }
  __bf16* dst = vt + ((size_t)bh * HD + d) * TT + tt * 64 + tc;
  *(bf16x8*)dst = o0;
  *(bf16x8*)(dst + 8) = o1;
}

// ---------------------------------------------------------------------------
// Causal flash attention v8 = v6 per-tile math + counted-vmcnt deep pipeline.
//   - TRIPLE-buffered K/V tiles; stage(t+2) issued at iter t.
//   - raw s_barrier + inline-asm s_waitcnt vmcnt(4): the 4 newest loads
//     (tile t+2) stay IN FLIGHT across the barrier; tile t+1 is forced
//     complete. vmcnt never drains to 0 in steady state (T4).
//   - each DMA has ~2 compute phases to land (vs 0.. in the 2-phase loop).
//   - exp2 via __builtin_amdgcn_exp2f (raw v_exp_f32, 1 instr vs OCML seq).
// LDS 56KB -> 2 blocks/CU (R4-R7 showed 2 vs 3 blocks/CU is neutral).
// grid = 1024 (32 chunks x 32 bh), LPT (longest chunk first).
// ---------------------------------------------------------------------------
__device__ __forceinline__ int psw(int row) {
  return (((row & 7) ^ ((row >> 3) & 7))) << 4;
}

__global__ __launch_bounds__(256, 2)
void attn_causal8(const __bf16* __restrict__ qkv, const __bf16* __restrict__ vt,
                  __bf16* __restrict__ yb) {
  __shared__ __align__(16) char Kbuf[3][8192];   // K[kv][d], chunk-swizzled
  __shared__ __align__(16) char Vbuf[3][8192];   // Vt[d][kv], chunk-swizzled
  __shared__ __align__(16) char Pbuf[4][2048];   // per-wave P[16][64], psw-swizzled

  const int tid = threadIdx.x;
  const int lane = tid & 63, w = tid >> 6;
  const int L = blockIdx.x;
  const int bh = L & 31;
  const int chunk = 31 - (L >> 5);               // LPT: longest first
  const int b = bh >> 4, h = bh & 15;
  const size_t rowbase = (size_t)b * TT;
  const int q0 = chunk * 64 + w * 16;
  const int fr = lane & 15, g = lane >> 4;
  const int ntiles = chunk + 1;

  bf16x8 qf[2];
#pragma unroll
  for (int kc = 0; kc < 2; kc++)
    qf[kc] = *(const bf16x8*)(qkv + (rowbase + q0 + fr) * QKVN + h * HD + kc * 32 + g * 8);

  bf16x8 ones;
#pragma unroll
  for (int j = 0; j < 8; j++) ones[j] = (__bf16)1.0f;

  f32x4 o[4];
  f32x4 lacc;
  float m[4];
#pragma unroll
  for (int n = 0; n < 4; n++)
#pragma unroll
    for (int r = 0; r < 4; r++) o[n][r] = 0.0f;
#pragma unroll
  for (int r = 0; r < 4; r++) { lacc[r] = 0.0f; m[r] = -1e30f; }

  // 4 gload_lds per thread per stage (W=4 -> vmcnt(4) = one stage in flight)
  auto stageKV = [&](int kt, int buf) {
#pragma unroll
    for (int i = 0; i < 2; i++) {
      const int c = tid + i * 256;
      const int row = c >> 3;
      const int c16 = (c & 7) ^ (row & 7);
      gload_lds16(qkv + (rowbase + kt * 64 + row) * QKVN + EMB + h * HD + c16 * 8,
                  Kbuf[buf] + c * 16);
    }
#pragma unroll
    for (int i = 0; i < 2; i++) {
      const int c = tid + i * 256;
      const int row = c >> 3;
      const int c16 = (c & 7) ^ (row & 7);
      gload_lds16(vt + ((size_t)bh * HD + row) * TT + kt * 64 + c16 * 8,
                  Vbuf[buf] + c * 16);
    }
  };

  // prologue: fill depth-2 pipeline, force tile 0 landed, keep tile 1 in flight
  stageKV(0, 0);
  if (ntiles > 1) {
    stageKV(1, 1);
    asm volatile("s_waitcnt vmcnt(4)" ::: "memory");
  } else {
    asm volatile("s_waitcnt vmcnt(0)" ::: "memory");
  }
  __builtin_amdgcn_s_barrier();
  __builtin_amdgcn_sched_barrier(0);

  int bcur = 0;
  for (int kt = 0; kt < ntiles; kt++) {
    // issue stage for tile kt+2 into the buffer freed at the last barrier
    if (kt + 2 < ntiles) {
      const int bn = (bcur + 2 >= 3) ? bcur - 1 : bcur + 2;
      stageKV(kt + 2, bn);
    }

    const int kv0 = kt * 64;
    bf16x8 kf[4][2];
#pragma unroll
    for (int n = 0; n < 4; n++)
#pragma unroll
      for (int kc = 0; kc < 2; kc++) {
        const int row = n * 16 + fr;
        kf[n][kc] = *(const bf16x8*)(Kbuf[bcur] + row * 128 + (((kc << 2) | g) ^ (row & 7)) * 16);
      }
    f32x4 s[4];
#pragma unroll
    for (int n = 0; n < 4; n++) {
#pragma unroll
      for (int r = 0; r < 4; r++) s[n][r] = 0.0f;
#pragma unroll
      for (int kc = 0; kc < 2; kc++)
        s[n] = __builtin_amdgcn_mfma_f32_16x16x32_bf16(qf[kc], kf[n][kc], s[n], 0, 0, 0);
    }
    if (kt == chunk) {                    // causal mask only on diagonal tile
#pragma unroll
      for (int n = 0; n < 4; n++)
#pragma unroll
        for (int r = 0; r < 4; r++) {
          const int qg = q0 + g * 4 + r;
          const int kg = kv0 + n * 16 + fr;
          if (kg > qg) s[n][r] = -1e30f;
        }
    }
    float pm[4];
#pragma unroll
    for (int r = 0; r < 4; r++)
      pm[r] = fmaxf(fmaxf(s[0][r], s[1][r]), fmaxf(s[2][r], s[3][r]));
    const bool ok = (pm[0] <= m[0] + THR) && (pm[1] <= m[1] + THR) &&
                    (pm[2] <= m[2] + THR) && (pm[3] <= m[3] + THR);
    if (!__all(ok)) {
#pragma unroll
      for (int r = 0; r < 4; r++) {
        float rm = pm[r];
#pragma unroll
        for (int d = 1; d < 16; d <<= 1) rm = fmaxf(rm, __shfl_xor(rm, d, 16));
        const float nm = fmaxf(m[r], rm);
        const float f = __builtin_amdgcn_exp2f(m[r] - nm);
        m[r] = nm;
        lacc[r] *= f;
#pragma unroll
        for (int n = 0; n < 4; n++) o[n][r] *= f;
      }
    }
#pragma unroll
    for (int n = 0; n < 4; n++)
#pragma unroll
      for (int r = 0; r < 4; r++) {
        const float e = __builtin_amdgcn_exp2f(s[n][r] - m[r]);
        const int row = g * 4 + r;
        *(__bf16*)(Pbuf[w] + row * 128 + (((n * 16 + fr) * 2) ^ psw(row))) = (__bf16)e;
      }
    bf16x8 pa[2];
#pragma unroll
    for (int kc = 0; kc < 2; kc++)
      pa[kc] = *(const bf16x8*)(Pbuf[w] + fr * 128 + ((kc * 64 + g * 16) ^ psw(fr)));
    bf16x8 vb[4][2];
#pragma unroll
    for (int n = 0; n < 4; n++)
#pragma unroll
      for (int kc = 0; kc < 2; kc++) {
        const int row = n * 16 + fr;
        vb[n][kc] = *(const bf16x8*)(Vbuf[bcur] + row * 128 + (((kc << 2) | g) ^ (row & 7)) * 16);
      }
#pragma unroll
    for (int kc = 0; kc < 2; kc++) {
      lacc = __builtin_amdgcn_mfma_f32_16x16x32_bf16(pa[kc], ones, lacc, 0, 0, 0);
#pragma unroll
      for (int n = 0; n < 4; n++)
        o[n] = __builtin_amdgcn_mfma_f32_16x16x32_bf16(pa[kc], vb[n][kc], o[n], 0, 0, 0);
    }

    // counted wait: tile kt+1 forced complete; tile kt+2's 4 loads stay in
    // flight across the barrier (never drain to 0 in steady state).
    if (kt + 2 < ntiles) asm volatile("s_waitcnt vmcnt(4)" ::: "memory");
    else                 asm volatile("s_waitcnt vmcnt(0)" ::: "memory");
    __builtin_amdgcn_s_barrier();
    __builtin_amdgcn_sched_barrier(0);
    bcur = (bcur + 1 == 3) ? 0 : bcur + 1;
  }

#pragma unroll
  for (int r = 0; r < 4; r++) {
    const float inv = __builtin_amdgcn_rcpf(lacc[r]);
#pragma unroll
    for (int n = 0; n < 4; n++) {
      const int q = q0 + g * 4 + r;
      const int d = n * 16 + fr;
      yb[(rowbase + q) * EMB + h * HD + d] = (__bf16)(o[n][r] * inv);
    }
  }
}

extern "C" void kernel_launch(void* const* d_in, const int* in_sizes, int n_in,
                              void* d_out, int out_size, void* d_ws, size_t ws_size,
                              hipStream_t stream) {
  const float* x     = (const float*)d_in[0];
  const float* w_qkv = (const float*)d_in[1];
  const float* w_out = (const float*)d_in[2];
  float* out = (float*)d_out;

  char* ws = (char*)d_ws;
  __bf16* xb    = (__bf16*)(ws);                 // reused as Vt after gemm1
  __bf16* wqkvb = (__bf16*)(ws + (8ull  << 20));
  __bf16* wob   = (__bf16*)(ws + (14ull << 20));
  __bf16* qkvb  = (__bf16*)(ws + (16ull << 20));
  __bf16* yb    = (__bf16*)(ws + (40ull << 20));
  __bf16* vtb   = xb;

  cvt_all<<<4096, 256, 0, stream>>>(x, w_qkv, w_out, xb, wqkvb, wob);
  gemm_bt<1, 1><<<dim3(QKVN / 128, NROWS / 128), 256, 0, stream>>>(xb, wqkvb, qkvb, NROWS, QKVN, EMB);
  vtrans<<<dim3(TT / 64, 32), 256, 0, stream>>>(qkvb, vtb);
  attn_causal8<<<1024, 256, 0, stream>>>(qkvb, vtb, yb);
  gemm_bt<0, 0><<<dim3(EMB / 128, NROWS / 128), 256, 0, stream>>>(yb, wob, out, NROWS, EMB, EMB);
}

// Round 9
// 115.339 us; speedup vs baseline: 1.0256x; 1.0033x over previous
//
#include <hip/hip_runtime.h>
#include <hip/hip_bf16.h>
#include <cstdint>

// ---------------------------------------------------------------------------
// Fused causal self-attention block (B=2, T=2048, C=1024, H=16, Dh=64), fp32 in/out.
// cvt fp32->bf16 -> QKV GEMM (Q pre-scaled) -> V-transpose -> causal flash attn -> out GEMM.
// Workspace (48MB):
//   xb/Vt @ 0     8 MB   bf16 x [4096][1024]; REUSED after gemm1 as Vt [32][64][2048]
//   wqkvb @ 8 MB  6 MB   bf16 w_qkv [3072][1024]
//   wob   @ 14MB  2 MB   bf16 w_out [1024][1024]
//   qkvb  @ 16MB 24 MB   bf16 qkv [4096][3072] (Q|K|V; Q scaled by 0.125*log2e)
//   yb    @ 40MB  8 MB   bf16 attn out [4096][1024]
// ---------------------------------------------------------------------------

typedef __bf16 bf16x8 __attribute__((ext_vector_type(8)));
typedef __bf16 bf16x2 __attribute__((ext_vector_type(2)));
typedef float  f32x4  __attribute__((ext_vector_type(4)));

#define EMB   1024
#define HEADS 16
#define HD    64
#define TT    2048
#define NROWS 4096
#define QKVN  3072
#define SCL   0.18033688f   /* 0.125 * log2(e): folded into Q at gemm1 epilogue */
#define THR   11.0f         /* defer-max threshold, log2 units */

// ---- fused fp32 -> bf16 (8 elems / thread, 3 arrays in one launch) ----
__global__ void cvt_all(const float* __restrict__ x, const float* __restrict__ wq,
                        const float* __restrict__ wo, __bf16* __restrict__ xb,
                        __bf16* __restrict__ wqb, __bf16* __restrict__ wob) {
  const int bid = blockIdx.x;
  const float* in; __bf16* out; int i;
  if (bid < 2048)      { in = x;  out = xb;  i = bid * 256 + threadIdx.x; }
  else if (bid < 3584) { in = wq; out = wqb; i = (bid - 2048) * 256 + threadIdx.x; }
  else                 { in = wo; out = wob; i = (bid - 3584) * 256 + threadIdx.x; }
  const float4* p = (const float4*)in + (size_t)i * 2;
  float4 a = p[0], b = p[1];
  bf16x8 o;
  o[0] = (__bf16)a.x; o[1] = (__bf16)a.y; o[2] = (__bf16)a.z; o[3] = (__bf16)a.w;
  o[4] = (__bf16)b.x; o[5] = (__bf16)b.y; o[6] = (__bf16)b.z; o[7] = (__bf16)b.w;
  *((bf16x8*)out + i) = o;
}

__device__ __forceinline__ void gload_lds16(const void* g, void* l) {
  __builtin_amdgcn_global_load_lds(
      (const __attribute__((address_space(1))) void*)(uintptr_t)g,
      (__attribute__((address_space(3))) void*)(uint32_t)(uintptr_t)l,
      16, 0, 0);
}

// ---- GEMM: C[M,N] = A[M,K] * Bm[N,K]^T (m97 structure + XCD swizzle) ----
template <int OUT_BF16, int SCALE_Q>
__global__ __launch_bounds__(256, 2)
void gemm_bt(const __bf16* __restrict__ A, const __bf16* __restrict__ Bm,
             void* __restrict__ Cout, int M, int N, int K) {
  __shared__ __align__(16) __bf16 As[128 * 32];
  __shared__ __align__(16) __bf16 Bs[128 * 32];
  const int tid  = threadIdx.x;
  const int lane = tid & 63;
  const int wid  = tid >> 6;
  const int wr = wid >> 1, wc = wid & 1;
  const int nwg = gridDim.x * gridDim.y;
  int flat = blockIdx.y * gridDim.x + blockIdx.x;
  flat = (flat & 7) * (nwg >> 3) + (flat >> 3);
  const int brow = (flat / gridDim.x) * 128;
  const int bcol = (flat % gridDim.x) * 128;
  const int fr = lane & 15, g = lane >> 4;

  f32x4 acc[4][4];
#pragma unroll
  for (int m = 0; m < 4; m++)
#pragma unroll
    for (int n = 0; n < 4; n++)
#pragma unroll
      for (int r = 0; r < 4; r++) acc[m][n][r] = 0.0f;

  const int c0 = tid, c1 = tid + 256;
  for (int k0 = 0; k0 < K; k0 += 32) {
    __syncthreads();
    gload_lds16(A  + (size_t)(brow + (c0 >> 2)) * K + k0 + (c0 & 3) * 8, (char*)As + c0 * 16);
    gload_lds16(A  + (size_t)(brow + (c1 >> 2)) * K + k0 + (c1 & 3) * 8, (char*)As + c1 * 16);
    gload_lds16(Bm + (size_t)(bcol + (c0 >> 2)) * K + k0 + (c0 & 3) * 8, (char*)Bs + c0 * 16);
    gload_lds16(Bm + (size_t)(bcol + (c1 >> 2)) * K + k0 + (c1 & 3) * 8, (char*)Bs + c1 * 16);
    __syncthreads();

    bf16x8 af[4], bfr[4];
#pragma unroll
    for (int m = 0; m < 4; m++)
      af[m] = *(const bf16x8*)((const char*)As + (wr * 64 + m * 16 + fr) * 64 + g * 16);
#pragma unroll
    for (int n = 0; n < 4; n++)
      bfr[n] = *(const bf16x8*)((const char*)Bs + (wc * 64 + n * 16 + fr) * 64 + g * 16);
#pragma unroll
    for (int m = 0; m < 4; m++)
#pragma unroll
      for (int n = 0; n < 4; n++)
        acc[m][n] = __builtin_amdgcn_mfma_f32_16x16x32_bf16(af[m], bfr[n], acc[m][n], 0, 0, 0);
  }

  const float qscale = (SCALE_Q && bcol < EMB) ? SCL : 1.0f;
  const int rbase = brow + wr * 64 + g * 4;
  const int cbase = bcol + wc * 64 + fr;
#pragma unroll
  for (int m = 0; m < 4; m++)
#pragma unroll
    for (int n = 0; n < 4; n++) {
      const int col = cbase + n * 16;
#pragma unroll
      for (int r = 0; r < 4; r++) {
        const int row = rbase + m * 16 + r;
        const float v = acc[m][n][r] * qscale;
        if (OUT_BF16) ((__bf16*)Cout)[(size_t)row * N + col] = (__bf16)v;
        else          ((float*)Cout)[(size_t)row * N + col]  = v;
      }
    }
}

// ---- V transpose: qkv [4096][3072] (V cols) -> Vt [32 bh][64 d][2048 t] ----
__global__ __launch_bounds__(256)
void vtrans(const __bf16* __restrict__ qkv, __bf16* __restrict__ vt) {
  __shared__ __bf16 tile[64][66];
  const int tt = blockIdx.x;
  const int bh = blockIdx.y;
  const int b = bh >> 4, h = bh & 15;
  const int tid = threadIdx.x;
  const int tl = tid >> 2, dq = (tid & 3) * 16;
  const __bf16* src = qkv + ((size_t)(b * TT + tt * 64 + tl)) * QKVN + 2 * EMB + h * HD + dq;
  bf16x8 v0 = *(const bf16x8*)src;
  bf16x8 v1 = *(const bf16x8*)(src + 8);
#pragma unroll
  for (int u = 0; u < 4; u++) {
    *(bf16x2*)&tile[tl][dq + 2 * u]     = bf16x2{v0[2 * u], v0[2 * u + 1]};
    *(bf16x2*)&tile[tl][dq + 8 + 2 * u] = bf16x2{v1[2 * u], v1[2 * u + 1]};
  }
  __syncthreads();
  const int d = tid >> 2, tc = (tid & 3) * 16;
  bf16x8 o0, o1;
#pragma unroll
  for (int j = 0; j < 8; j++) { o0[j] = tile[tc + j][d]; o1[j] = tile[tc + 8 + j][d]; }
  __bf16* dst = vt + ((size_t)bh * HD + d) * TT + tt * 64 + tc;
  *(bf16x8*)dst = o0;
  *(bf16x8*)(dst + 8) = o1;
}

// ---------------------------------------------------------------------------
// Causal flash attention v9 = v8 math + cross-tile software pipeline.
//   Iter t: stage(t+3) | QK(t+1) | PV(t) | softmax(t+1)+P-write(t+1).
//   - P's LDS write->read round-trip spans a full phase (hidden).
//   - kf-read(t+1) latency hides under PV(t); pa/vb reads hide under QK MFMAs.
//   - 4-deep K/V buffers; end-of-iter s_waitcnt vmcnt(4) forces tile t+2
//     landed (needed by next iter's QK) while t+3's 4 loads stay in flight
//     across the barrier (counted wait, T4).
//   - same-wave DS ordering guarantees pa-read(t) < P-write(t+1). Wave-
//     private Pbuf; no extra barriers.
// LDS 72KB -> 2 blocks/CU. grid = 1024 (32 chunks x 32 bh), LPT order.
// ---------------------------------------------------------------------------
__device__ __forceinline__ int psw(int row) {
  return (((row & 7) ^ ((row >> 3) & 7))) << 4;
}

__global__ __launch_bounds__(256, 2)
void attn_causal9(const __bf16* __restrict__ qkv, const __bf16* __restrict__ vt,
                  __bf16* __restrict__ yb) {
  __shared__ __align__(16) char Kbuf[4][8192];   // K[kv][d], chunk-swizzled
  __shared__ __align__(16) char Vbuf[4][8192];   // Vt[d][kv], chunk-swizzled
  __shared__ __align__(16) char Pbuf[4][2048];   // per-wave P[16][64], psw-swizzled

  const int tid = threadIdx.x;
  const int lane = tid & 63, w = tid >> 6;
  const int L = blockIdx.x;
  const int bh = L & 31;
  const int chunk = 31 - (L >> 5);               // LPT: longest first
  const int b = bh >> 4, h = bh & 15;
  const size_t rowbase = (size_t)b * TT;
  const int q0 = chunk * 64 + w * 16;
  const int fr = lane & 15, g = lane >> 4;
  const int ntiles = chunk + 1;

  bf16x8 qf[2];
#pragma unroll
  for (int kc = 0; kc < 2; kc++)
    qf[kc] = *(const bf16x8*)(qkv + (rowbase + q0 + fr) * QKVN + h * HD + kc * 32 + g * 8);

  bf16x8 ones;
#pragma unroll
  for (int j = 0; j < 8; j++) ones[j] = (__bf16)1.0f;

  f32x4 o[4];
  f32x4 lacc;
  float m[4];
#pragma unroll
  for (int n = 0; n < 4; n++)
#pragma unroll
    for (int r = 0; r < 4; r++) o[n][r] = 0.0f;
#pragma unroll
  for (int r = 0; r < 4; r++) { lacc[r] = 0.0f; m[r] = -1e30f; }

  // 4 gload_lds per thread per stage -> vmcnt(4) = one stage in flight
  auto stageKV = [&](int kt, int buf) {
#pragma unroll
    for (int i = 0; i < 2; i++) {
      const int c = tid + i * 256;
      const int row = c >> 3;
      const int c16 = (c & 7) ^ (row & 7);
      gload_lds16(qkv + (rowbase + kt * 64 + row) * QKVN + EMB + h * HD + c16 * 8,
                  Kbuf[buf] + c * 16);
    }
#pragma unroll
    for (int i = 0; i < 2; i++) {
      const int c = tid + i * 256;
      const int row = c >> 3;
      const int c16 = (c & 7) ^ (row & 7);
      gload_lds16(vt + ((size_t)bh * HD + row) * TT + kt * 64 + c16 * 8,
                  Vbuf[buf] + c * 16);
    }
  };

  // QK for tile kt (reads Kbuf[kt&3]) -> s
  auto doQK = [&](int kt, f32x4 (&s)[4]) {
    const char* Kc = Kbuf[kt & 3];
    bf16x8 kf[4][2];
#pragma unroll
    for (int n = 0; n < 4; n++)
#pragma unroll
      for (int kc = 0; kc < 2; kc++) {
        const int row = n * 16 + fr;
        kf[n][kc] = *(const bf16x8*)(Kc + row * 128 + (((kc << 2) | g) ^ (row & 7)) * 16);
      }
#pragma unroll
    for (int n = 0; n < 4; n++) {
#pragma unroll
      for (int r = 0; r < 4; r++) s[n][r] = 0.0f;
#pragma unroll
      for (int kc = 0; kc < 2; kc++)
        s[n] = __builtin_amdgcn_mfma_f32_16x16x32_bf16(qf[kc], kf[n][kc], s[n], 0, 0, 0);
    }
  };

  // softmax for tile kt: mask, defer-max vote/rescale, exp2, P-write
  auto doSoftmax = [&](int kt, f32x4 (&s)[4]) {
    const int kv0 = kt * 64;
    if (kt == chunk) {
#pragma unroll
      for (int n = 0; n < 4; n++)
#pragma unroll
        for (int r = 0; r < 4; r++) {
          const int qg = q0 + g * 4 + r;
          const int kg = kv0 + n * 16 + fr;
          if (kg > qg) s[n][r] = -1e30f;
        }
    }
    float pm[4];
#pragma unroll
    for (int r = 0; r < 4; r++)
      pm[r] = fmaxf(fmaxf(s[0][r], s[1][r]), fmaxf(s[2][r], s[3][r]));
    const bool ok = (pm[0] <= m[0] + THR) && (pm[1] <= m[1] + THR) &&
                    (pm[2] <= m[2] + THR) && (pm[3] <= m[3] + THR);
    if (!__all(ok)) {
#pragma unroll
      for (int r = 0; r < 4; r++) {
        float rm = pm[r];
#pragma unroll
        for (int d = 1; d < 16; d <<= 1) rm = fmaxf(rm, __shfl_xor(rm, d, 16));
        const float nm = fmaxf(m[r], rm);
        const float f = __builtin_amdgcn_exp2f(m[r] - nm);
        m[r] = nm;
        lacc[r] *= f;
#pragma unroll
        for (int n = 0; n < 4; n++) o[n][r] *= f;
      }
    }
#pragma unroll
    for (int n = 0; n < 4; n++)
#pragma unroll
      for (int r = 0; r < 4; r++) {
        const float e = __builtin_amdgcn_exp2f(s[n][r] - m[r]);
        const int row = g * 4 + r;
        *(__bf16*)(Pbuf[w] + row * 128 + (((n * 16 + fr) * 2) ^ psw(row))) = (__bf16)e;
      }
  };

  // PV for tile kt: pa/vb reads + 10 MFMA (lacc via ones)
  auto doPV = [&](int kt) {
    const char* Vc = Vbuf[kt & 3];
    bf16x8 pa[2];
#pragma unroll
    for (int kc = 0; kc < 2; kc++)
      pa[kc] = *(const bf16x8*)(Pbuf[w] + fr * 128 + ((kc * 64 + g * 16) ^ psw(fr)));
    bf16x8 vb[4][2];
#pragma unroll
    for (int n = 0; n < 4; n++)
#pragma unroll
      for (int kc = 0; kc < 2; kc++) {
        const int row = n * 16 + fr;
        vb[n][kc] = *(const bf16x8*)(Vc + row * 128 + (((kc << 2) | g) ^ (row & 7)) * 16);
      }
#pragma unroll
    for (int kc = 0; kc < 2; kc++) {
      lacc = __builtin_amdgcn_mfma_f32_16x16x32_bf16(pa[kc], ones, lacc, 0, 0, 0);
#pragma unroll
      for (int n = 0; n < 4; n++)
        o[n] = __builtin_amdgcn_mfma_f32_16x16x32_bf16(pa[kc], vb[n][kc], o[n], 0, 0, 0);
    }
  };

  // ---- prologue: fill pipeline (tiles 0..2), force 0,1 landed ----
  stageKV(0, 0);
  if (ntiles > 1) stageKV(1, 1);
  if (ntiles > 2) stageKV(2, 2);
  if (ntiles > 2) asm volatile("s_waitcnt vmcnt(4)" ::: "memory");
  else            asm volatile("s_waitcnt vmcnt(0)" ::: "memory");
  __builtin_amdgcn_s_barrier();

  {                                   // tile 0: QK + softmax (P ready for loop)
    f32x4 s0[4];
    doQK(0, s0);
    doSoftmax(0, s0);
  }

  for (int t = 0; t < ntiles; t++) {
    if (t + 3 < ntiles) stageKV(t + 3, (t + 3) & 3);

    const bool nxt = (t + 1 < ntiles);
    f32x4 s[4];
    if (nxt) doQK(t + 1, s);          // independent stream: overlaps PV(t)
    doPV(t);                          // consumes P(t) written last iter
    if (nxt) doSoftmax(t + 1, s);     // rescale o AFTER PV(t); writes P(t+1)

    if (t + 3 < ntiles) asm volatile("s_waitcnt vmcnt(4)" ::: "memory");
    else                asm volatile("s_waitcnt vmcnt(0)" ::: "memory");
    __builtin_amdgcn_s_barrier();
  }

#pragma unroll
  for (int r = 0; r < 4; r++) {
    const float inv = __builtin_amdgcn_rcpf(lacc[r]);
#pragma unroll
    for (int n = 0; n < 4; n++) {
      const int q = q0 + g * 4 + r;
      const int d = n * 16 + fr;
      yb[(rowbase + q) * EMB + h * HD + d] = (__bf16)(o[n][r] * inv);
    }
  }
}

extern "C" void kernel_launch(void* const* d_in, const int* in_sizes, int n_in,
                              void* d_out, int out_size, void* d_ws, size_t ws_size,
                              hipStream_t stream) {
  const float* x     = (const float*)d_in[0];
  const float* w_qkv = (const float*)d_in[1];
  const float* w_out = (const float*)d_in[2];
  float* out = (float*)d_out;

  char* ws = (char*)d_ws;
  __bf16* xb    = (__bf16*)(ws);                 // reused as Vt after gemm1
  __bf16* wqkvb = (__bf16*)(ws + (8ull  << 20));
  __bf16* wob   = (__bf16*)(ws + (14ull << 20));
  __bf16* qkvb  = (__bf16*)(ws + (16ull << 20));
  __bf16* yb    = (__bf16*)(ws + (40ull << 20));
  __bf16* vtb   = xb;

  cvt_all<<<4096, 256, 0, stream>>>(x, w_qkv, w_out, xb, wqkvb, wob);
  gemm_bt<1, 1><<<dim3(QKVN / 128, NROWS / 128), 256, 0, stream>>>(xb, wqkvb, qkvb, NROWS, QKVN, EMB);
  vtrans<<<dim3(TT / 64, 32), 256, 0, stream>>>(qkvb, vtb);
  attn_causal9<<<1024, 256, 0, stream>>>(qkvb, vtb, yb);
  gemm_bt<0, 0><<<dim3(EMB / 128, NROWS / 128), 256, 0, stream>>>(yb, wob, out, NROWS, EMB, EMB);
}